// Round 2
// baseline (1135.529 us; speedup 1.0000x reference)
//
#include <hip/hip_runtime.h>

// Problem constants (B=2, H=16, L=2048, D=64 — fixed by the reference setup).
#define BH   32
#define LSEQ 2048
#define DDIM 64
#define ERRC 1e-12f

typedef __attribute__((ext_vector_type(8)))  short bf16x8;
typedef __attribute__((ext_vector_type(4)))  float floatx4;
typedef __attribute__((ext_vector_type(16))) float floatx16;
typedef __attribute__((ext_vector_type(4)))  unsigned short ushort4v;

// float -> bf16 round-to-nearest-even (inputs are finite, no NaN handling needed)
__device__ __forceinline__ unsigned short f2bf(float f) {
    unsigned u = __float_as_uint(f);
    u = u + 0x7FFFu + ((u >> 16) & 1u);
    return (unsigned short)(u >> 16);
}

__device__ __forceinline__ bf16x8 pack8s(const float* __restrict__ p, float w) {
    const floatx4* pv = (const floatx4*)p;
    floatx4 x = pv[0], y = pv[1];
    bf16x8 r;
    r[0] = (short)f2bf(x[0] * w); r[1] = (short)f2bf(x[1] * w);
    r[2] = (short)f2bf(x[2] * w); r[3] = (short)f2bf(x[3] * w);
    r[4] = (short)f2bf(y[0] * w); r[5] = (short)f2bf(y[1] * w);
    r[6] = (short)f2bf(y[2] * w); r[7] = (short)f2bf(y[3] * w);
    return r;
}

// Prep: ks = bf16(k * sqrt(src+err)), kd = bf16(k * sqrt(dest+err)).
__global__ __launch_bounds__(256) void prep_scaled(const float* __restrict__ k,
                                                   const float* __restrict__ src,
                                                   const float* __restrict__ dest,
                                                   unsigned short* __restrict__ ks,
                                                   unsigned short* __restrict__ kd) {
    int idx4 = blockIdx.x * 256 + threadIdx.x;
    int row  = idx4 >> 4;                     // 16 float4 per 64-wide row
    float s = sqrtf(src[row] + ERRC);
    float d = sqrtf(dest[row] + ERRC);
    floatx4 v = ((const floatx4*)k)[idx4];
    ushort4v os, od;
#pragma unroll
    for (int r = 0; r < 4; ++r) { os[r] = f2bf(v[r] * s); od[r] = f2bf(v[r] * d); }
    ((ushort4v*)ks)[idx4] = os;
    ((ushort4v*)kd)[idx4] = od;
}

// Load the 4 K-fragments (K=64 split into 4x16) of one row for the 32x32x16 MFMA.
// Operand layout: row = lane&31, k = (lane>>5)*8 + t within each K=16 slice.
// frag f covers elements f*16 + h*8 .. +8  (h = lane>>5).
template<bool RAW>
__device__ __forceinline__ void load_frags(const void* __restrict__ kp, long base, int row,
                                           int h, const float* __restrict__ w, int bhL,
                                           bf16x8& f0, bf16x8& f1, bf16x8& f2, bf16x8& f3) {
    if (RAW) {
        const float* p = (const float*)kp + base + (long)row * DDIM + h * 8;
        float s = sqrtf(w[bhL + row] + ERRC);
        f0 = pack8s(p, s);      f1 = pack8s(p + 16, s);
        f2 = pack8s(p + 32, s); f3 = pack8s(p + 48, s);
    } else {
        const unsigned short* p = (const unsigned short*)kp + base + (long)row * DDIM + h * 8;
        f0 = *(const bf16x8*)p;        f1 = *(const bf16x8*)(p + 16);
        f2 = *(const bf16x8*)(p + 32); f3 = *(const bf16x8*)(p + 48);
    }
}

// One wave = one 32-column i-tile; streams 64 j-tiles of 32 rows.
// Swapped MFMA: D = kd_tile(j rows) . ks_rows(i)^T -> D[m=j][n=i].
// C/D 32x32 layout: col(lane&31)=i, row = (reg&3) + 8*(reg>>2) + 4*(lane>>5) = j_local.
// So lane (h=lane>>5, c=lane&31) holds, for output row i0+c, the j values
// {8g+4h+r : g=0..3, r=0..3} — 4 groups of 4 CONSECUTIVE j, in-lane.
template<bool RAW>
__global__ __launch_bounds__(256) void mha_fused3(const void* __restrict__ ka,   // kd (or raw k)
                                                  const void* __restrict__ kb,   // ks (or raw k)
                                                  const float* __restrict__ src,
                                                  const float* __restrict__ dest,
                                                  float* __restrict__ out) {
    const int tid  = threadIdx.x;
    const int wave = tid >> 6;
    const int lane = tid & 63;
    const int c    = lane & 31;
    const int h    = lane >> 5;
    // bh in low bits: same-bh blocks are 32 apart -> same XCD under mod-8 dispatch.
    const int bh = blockIdx.x & 31;
    const int ib = blockIdx.x >> 5;           // 0..15
    const int i0 = (ib * 4 + wave) * 32;      // this wave's 32-column (i) tile
    const int bhL = bh * LSEQ;
    const long base = (long)bh * LSEQ * DDIM;

    // B operand: ks row i0+c, held for the whole kernel
    bf16x8 b0, b1, b2, b3;
    load_frags<RAW>(kb, base, i0 + c, h, src, bhL, b0, b1, b2, b3);

    float carry = 0.f;                        // running row sum for output row i0+c
    const float c23 = 2.0f / 3.0f;

    // prefetch j-tile 0
    bf16x8 a0, a1, a2, a3;
    load_frags<RAW>(ka, base, c, h, dest, bhL, a0, a1, a2, a3);

    // lane's output row; its column groups start at 4h + 8g
    float* orow = out + (long)(bhL + i0 + c) * LSEQ + 4 * h;

    for (int jt = 0; jt < 64; ++jt) {
        const int j0 = jt << 5;

        // prefetch next j-tile (redundant reload of tile 0 on last iter)
        bf16x8 n0, n1, n2, n3;
        const int jn = (jt < 63) ? (jt + 1) << 5 : 0;
        load_frags<RAW>(ka, base, jn + c, h, dest, bhL, n0, n1, n2, n3);

        floatx16 acc;
#pragma unroll
        for (int e = 0; e < 16; ++e) acc[e] = 0.f;
        acc = __builtin_amdgcn_mfma_f32_32x32x16_bf16(a0, b0, acc, 0, 0, 0);
        acc = __builtin_amdgcn_mfma_f32_32x32x16_bf16(a1, b1, acc, 0, 0, 0);
        acc = __builtin_amdgcn_mfma_f32_32x32x16_bf16(a2, b2, acc, 0, 0, 0);
        acc = __builtin_amdgcn_mfma_f32_32x32x16_bf16(a3, b3, acc, 0, 0, 0);

        // a3 = exp2(log2(relu(a1)+err) * 2/3) — 16 independent elements for ILP
        float u[16];
#pragma unroll
        for (int e = 0; e < 16; ++e) {
            float v = fmaxf(acc[e], 0.f) + ERRC;
            u[e] = exp2f(c23 * __log2f(v));
        }

        if (j0 + 32 <= i0) {
            // fully masked tile: only the total feeds the carry
            float s = (((u[0] + u[1]) + (u[2] + u[3])) + ((u[4] + u[5]) + (u[6] + u[7])))
                    + (((u[8] + u[9]) + (u[10] + u[11])) + ((u[12] + u[13]) + (u[14] + u[15])));
            carry += s + __shfl_xor(s, 32, 64);
            const floatx4 z = {0.f, 0.f, 0.f, 0.f};
#pragma unroll
            for (int g = 0; g < 4; ++g)
                __builtin_nontemporal_store(z, (floatx4*)(orow + 8 * g));
        } else {
            // in-lane inclusive prefix within each 4-wide group
#pragma unroll
            for (int g = 0; g < 4; ++g) {
                u[4 * g + 1] += u[4 * g + 0];
                u[4 * g + 2] += u[4 * g + 1];
                u[4 * g + 3] += u[4 * g + 2];
            }
            const float S0 = u[3], S1 = u[7], S2 = u[11], S3 = u[15];
            // partner (h^1) group sums — 4 INDEPENDENT shuffles, no serial chain
            const float P0 = __shfl_xor(S0, 32, 64);
            const float P1 = __shfl_xor(S1, 32, 64);
            const float P2 = __shfl_xor(S2, 32, 64);
            const float P3 = __shfl_xor(S3, 32, 64);
            const float q0 = S0 + P0, q1 = S1 + P1, q2 = S2 + P2, q3 = S3 + P3;
            // exclusive chunk-prefix (chunks ordered by j-base 8g+4h), carry folded in
            const float e0 = carry;
            const float e1 = e0 + q0;
            const float e2 = e1 + q1;
            const float e3 = e2 + q2;
            carry = e3 + q3;                  // tile total — both lanes agree, no broadcast
            const float hx = (h != 0) ? 1.f : 0.f;
            const float E0 = e0 + hx * P0, E1 = e1 + hx * P1,
                        E2 = e2 + hx * P2, E3 = e3 + hx * P3;

            if (j0 == i0) {                   // the single mixed (diagonal) tile
#pragma unroll
                for (int g = 0; g < 4; ++g) {
                    const float Eg = (g == 0) ? E0 : (g == 1) ? E1 : (g == 2) ? E2 : E3;
                    floatx4 o;
#pragma unroll
                    for (int r = 0; r < 4; ++r)
                        o[r] = ((8 * g + 4 * h + r) >= c) ? (u[4 * g + r] + Eg) : 0.f;
                    __builtin_nontemporal_store(o, (floatx4*)(orow + 8 * g));
                }
            } else {                          // fully above diagonal
#pragma unroll
                for (int g = 0; g < 4; ++g) {
                    const float Eg = (g == 0) ? E0 : (g == 1) ? E1 : (g == 2) ? E2 : E3;
                    floatx4 o;
#pragma unroll
                    for (int r = 0; r < 4; ++r)
                        o[r] = u[4 * g + r] + Eg;
                    __builtin_nontemporal_store(o, (floatx4*)(orow + 8 * g));
                }
            }
        }

        orow += 32;
        a0 = n0; a1 = n1; a2 = n2; a3 = n3;
    }
}

extern "C" void kernel_launch(void* const* d_in, const int* in_sizes, int n_in,
                              void* d_out, int out_size, void* d_ws, size_t ws_size,
                              hipStream_t stream) {
    const float* k    = (const float*)d_in[0];
    const float* src  = (const float*)d_in[1];
    const float* dest = (const float*)d_in[2];
    float* out = (float*)d_out;

    const size_t half = (size_t)BH * LSEQ * DDIM * sizeof(unsigned short); // 8 MiB
    if (ws_size >= 2 * half) {
        unsigned short* ks = (unsigned short*)d_ws;
        unsigned short* kd = (unsigned short*)((char*)d_ws + half);
        prep_scaled<<<dim3(4096), dim3(256), 0, stream>>>(k, src, dest, ks, kd);
        mha_fused3<false><<<dim3(512), dim3(256), 0, stream>>>(kd, ks, src, dest, out);
    } else {
        mha_fused3<true><<<dim3(512), dim3(256), 0, stream>>>(k, k, src, dest, out);
    }
}

// Round 3
// 625.343 us; speedup vs baseline: 1.8158x; 1.8158x over previous
//
#include <hip/hip_runtime.h>

// Problem constants (B=2, H=16, L=2048, D=64 — fixed by the reference setup).
#define BH   32
#define LSEQ 2048
#define DDIM 64
#define ERRC 1e-12f

typedef __attribute__((ext_vector_type(8)))  short bf16x8;
typedef __attribute__((ext_vector_type(4)))  float floatx4;
typedef __attribute__((ext_vector_type(4)))  unsigned short ushort4v;

// float -> bf16 round-to-nearest-even (inputs are finite, no NaN handling needed)
__device__ __forceinline__ unsigned short f2bf(float f) {
    unsigned u = __float_as_uint(f);
    u = u + 0x7FFFu + ((u >> 16) & 1u);
    return (unsigned short)(u >> 16);
}

__device__ __forceinline__ bf16x8 pack8s(const float* __restrict__ p, float w) {
    const floatx4* pv = (const floatx4*)p;
    floatx4 x = pv[0], y = pv[1];
    bf16x8 r;
    r[0] = (short)f2bf(x[0] * w); r[1] = (short)f2bf(x[1] * w);
    r[2] = (short)f2bf(x[2] * w); r[3] = (short)f2bf(x[3] * w);
    r[4] = (short)f2bf(y[0] * w); r[5] = (short)f2bf(y[1] * w);
    r[6] = (short)f2bf(y[2] * w); r[7] = (short)f2bf(y[3] * w);
    return r;
}

// Prep: ks = bf16(k * sqrt(src+err)), kd = bf16(k * sqrt(dest+err)).
__global__ __launch_bounds__(256) void prep_scaled(const float* __restrict__ k,
                                                   const float* __restrict__ src,
                                                   const float* __restrict__ dest,
                                                   unsigned short* __restrict__ ks,
                                                   unsigned short* __restrict__ kd) {
    int idx4 = blockIdx.x * 256 + threadIdx.x;
    int row  = idx4 >> 4;                     // 16 float4 per 64-wide row
    float s = sqrtf(src[row] + ERRC);
    float d = sqrtf(dest[row] + ERRC);
    floatx4 v = ((const floatx4*)k)[idx4];
    ushort4v os, od;
#pragma unroll
    for (int r = 0; r < 4; ++r) { os[r] = f2bf(v[r] * s); od[r] = f2bf(v[r] * d); }
    ((ushort4v*)ks)[idx4] = os;
    ((ushort4v*)kd)[idx4] = od;
}

// Load one 16-row MFMA operand fragment pair (K=64 split as k<32 / k>=32).
// Layout for 16x16x32: row = lane&15, k = (lane>>4)*8 + t.
template<bool RAW>
__device__ __forceinline__ void load_row16(const void* __restrict__ kp, long base, int row,
                                           int q, const float* __restrict__ w, int bhL,
                                           bf16x8& lo, bf16x8& hi) {
    if (RAW) {
        const float* p = (const float*)kp + base + (long)row * DDIM + q * 8;
        float s = sqrtf(w[bhL + row] + ERRC);
        lo = pack8s(p, s);
        hi = pack8s(p + 32, s);
    } else {
        const unsigned short* p = (const unsigned short*)kp + base + (long)row * DDIM + q * 8;
        lo = *(const bf16x8*)p;
        hi = *(const bf16x8*)(p + 32);
    }
}

// One wave = one 16-column i-tile; streams 32 iterations of 64 j (4 16-row tiles).
// Swapped MFMA: D = kd_tile(j rows) . ks_rows(i)^T -> D[m=j][n=i],
// C/D: col(l16)=i, row(q*4+r)=j -> each lane holds 4 CONSECUTIVE j per tile, in-lane.
template<bool RAW>
__global__ __launch_bounds__(256, 4) void mha_fused4(const void* __restrict__ ka,  // kd (or raw k)
                                                     const void* __restrict__ kb,  // ks (or raw k)
                                                     const float* __restrict__ src,
                                                     const float* __restrict__ dest,
                                                     float* __restrict__ out) {
    const int tid  = threadIdx.x;
    const int wave = tid >> 6;
    const int lane = tid & 63;
    const int q    = lane >> 4;
    const int l16  = lane & 15;
    // bh in low bits: same-bh blocks are 32 apart -> same XCD under mod-8 dispatch.
    const int bh = blockIdx.x & 31;
    const int ib = blockIdx.x >> 5;           // 0..31
    const int i0 = (ib * 4 + wave) * 16;      // this wave's 16-column (i) tile
    const int bhL = bh * LSEQ;
    const long base = (long)bh * LSEQ * DDIM;

    // B operand: ks row i0+l16, held for the whole kernel
    bf16x8 blo, bhi;
    load_row16<RAW>(kb, base, i0 + l16, q, src, bhL, blo, bhi);

    float carry = 0.f;                        // running row sum for output row i0+l16
    const float c23 = 2.0f / 3.0f;

    // prefetch j-tiles 0..3
    bf16x8 aLo[4], aHi[4];
#pragma unroll
    for (int t = 0; t < 4; ++t)
        load_row16<RAW>(ka, base, 16 * t + l16, q, dest, bhL, aLo[t], aHi[t]);

    float* orow = out + (long)(bhL + i0 + l16) * LSEQ + q * 4;

    for (int it = 0; it < 32; ++it) {
        const int j0 = it << 6;

        // prefetch next iteration's 4 tiles (redundant reload of tiles 0..3 on last iter)
        bf16x8 nLo[4], nHi[4];
        const int jn = (it < 31) ? (j0 + 64) : 0;
#pragma unroll
        for (int t = 0; t < 4; ++t)
            load_row16<RAW>(ka, base, jn + 16 * t + l16, q, dest, bhL, nLo[t], nHi[t]);

        // 8 MFMAs, independent across the 4 tiles
        floatx4 acc[4];
#pragma unroll
        for (int t = 0; t < 4; ++t) {
            floatx4 z = {0.f, 0.f, 0.f, 0.f};
            z = __builtin_amdgcn_mfma_f32_16x16x32_bf16(aLo[t], blo, z, 0, 0, 0);
            acc[t] = __builtin_amdgcn_mfma_f32_16x16x32_bf16(aHi[t], bhi, z, 0, 0, 0);
        }

        // a3 = exp2(log2(relu(a1)+err) * 2/3) — 16 independent elements
        float u[4][4];
#pragma unroll
        for (int t = 0; t < 4; ++t)
#pragma unroll
            for (int r = 0; r < 4; ++r) {
                float v = fmaxf(acc[t][r], 0.f) + ERRC;
                u[t][r] = exp2f(c23 * __log2f(v));
            }

        if (j0 + 64 <= i0) {
            // all 4 tiles fully below the diagonal: only the strip total feeds the carry
            float s = 0.f;
#pragma unroll
            for (int t = 0; t < 4; ++t)
                s += (u[t][0] + u[t][1]) + (u[t][2] + u[t][3]);
            float s1 = s + __shfl_xor(s, 16, 64);
            carry += s1 + __shfl_xor(s1, 32, 64);
            const floatx4 z = {0.f, 0.f, 0.f, 0.f};
#pragma unroll
            for (int t = 0; t < 4; ++t)
                *(floatx4*)(orow + j0 + 16 * t) = z;
        } else {
#pragma unroll
            for (int t = 0; t < 4; ++t) {
                const int jt0 = j0 + 16 * t;
                if (jt0 + 16 <= i0) {
                    // fully masked tile: total only
                    float s = (u[t][0] + u[t][1]) + (u[t][2] + u[t][3]);
                    float s1 = s + __shfl_xor(s, 16, 64);
                    carry += s1 + __shfl_xor(s1, 32, 64);
                    const floatx4 z = {0.f, 0.f, 0.f, 0.f};
                    *(floatx4*)(orow + jt0) = z;
                } else {
                    // in-lane inclusive prefix over this lane's 4 consecutive j
                    u[t][1] += u[t][0];
                    u[t][2] += u[t][1];
                    u[t][3] += u[t][2];
                    const float S   = u[t][3];
                    const float x16 = __shfl_xor(S, 16, 64);
                    const float s1  = S + x16;
                    const float x32 = __shfl_xor(s1, 32, 64);
                    // exclusive prefix over the 4 q-chunks + running carry
                    const float E = ((q & 1) ? x16 : 0.f) + ((q & 2) ? x32 : 0.f) + carry;
                    carry += s1 + x32;        // tile total — identical in all lanes of the group
                    floatx4 o;
                    if (jt0 == i0) {          // the single mixed (diagonal) tile
#pragma unroll
                        for (int r = 0; r < 4; ++r)
                            o[r] = ((q * 4 + r) >= l16) ? (u[t][r] + E) : 0.f;
                    } else {                  // fully above diagonal
#pragma unroll
                        for (int r = 0; r < 4; ++r)
                            o[r] = u[t][r] + E;
                    }
                    *(floatx4*)(orow + jt0) = o;
                }
            }
        }

#pragma unroll
        for (int t = 0; t < 4; ++t) { aLo[t] = nLo[t]; aHi[t] = nHi[t]; }
    }
}

extern "C" void kernel_launch(void* const* d_in, const int* in_sizes, int n_in,
                              void* d_out, int out_size, void* d_ws, size_t ws_size,
                              hipStream_t stream) {
    const float* k    = (const float*)d_in[0];
    const float* src  = (const float*)d_in[1];
    const float* dest = (const float*)d_in[2];
    float* out = (float*)d_out;

    const size_t half = (size_t)BH * LSEQ * DDIM * sizeof(unsigned short); // 8 MiB
    if (ws_size >= 2 * half) {
        unsigned short* ks = (unsigned short*)d_ws;
        unsigned short* kd = (unsigned short*)((char*)d_ws + half);
        prep_scaled<<<dim3(4096), dim3(256), 0, stream>>>(k, src, dest, ks, kd);
        mha_fused4<false><<<dim3(1024), dim3(256), 0, stream>>>(kd, ks, src, dest, out);
    } else {
        mha_fused4<true><<<dim3(1024), dim3(256), 0, stream>>>(k, k, src, dest, out);
    }
}

// Round 4
// 613.548 us; speedup vs baseline: 1.8508x; 1.0192x over previous
//
#include <hip/hip_runtime.h>

// Problem constants (B=2, H=16, L=2048, D=64 — fixed by the reference setup).
#define BH   32
#define LSEQ 2048
#define DDIM 64
#define ERRC 1e-12f
#define SROW 129   // LDS strip row stride in floats (128 cols + 1 pad, breaks bank alias)

typedef __attribute__((ext_vector_type(8)))  short bf16x8;
typedef __attribute__((ext_vector_type(4)))  float floatx4;
typedef __attribute__((ext_vector_type(4)))  unsigned short ushort4v;

// float -> bf16 round-to-nearest-even (inputs are finite, no NaN handling needed)
__device__ __forceinline__ unsigned short f2bf(float f) {
    unsigned u = __float_as_uint(f);
    u = u + 0x7FFFu + ((u >> 16) & 1u);
    return (unsigned short)(u >> 16);
}

__device__ __forceinline__ bf16x8 pack8s(const float* __restrict__ p, float w) {
    const floatx4* pv = (const floatx4*)p;
    floatx4 x = pv[0], y = pv[1];
    bf16x8 r;
    r[0] = (short)f2bf(x[0] * w); r[1] = (short)f2bf(x[1] * w);
    r[2] = (short)f2bf(x[2] * w); r[3] = (short)f2bf(x[3] * w);
    r[4] = (short)f2bf(y[0] * w); r[5] = (short)f2bf(y[1] * w);
    r[6] = (short)f2bf(y[2] * w); r[7] = (short)f2bf(y[3] * w);
    return r;
}

// Prep: ks = bf16(k * sqrt(src+err)), kd = bf16(k * sqrt(dest+err)).
__global__ __launch_bounds__(256) void prep_scaled(const float* __restrict__ k,
                                                   const float* __restrict__ src,
                                                   const float* __restrict__ dest,
                                                   unsigned short* __restrict__ ks,
                                                   unsigned short* __restrict__ kd) {
    int idx4 = blockIdx.x * 256 + threadIdx.x;
    int row  = idx4 >> 4;                     // 16 float4 per 64-wide row
    float s = sqrtf(src[row] + ERRC);
    float d = sqrtf(dest[row] + ERRC);
    floatx4 v = ((const floatx4*)k)[idx4];
    ushort4v os, od;
#pragma unroll
    for (int r = 0; r < 4; ++r) { os[r] = f2bf(v[r] * s); od[r] = f2bf(v[r] * d); }
    ((ushort4v*)ks)[idx4] = os;
    ((ushort4v*)kd)[idx4] = od;
}

// Load one 16-row MFMA operand fragment pair (K=64 split as k<32 / k>=32).
// Layout for 16x16x32: row = lane&15, k = (lane>>4)*8 + t.
template<bool RAW>
__device__ __forceinline__ void load_row16(const void* __restrict__ kp, long base, int row,
                                           int q, const float* __restrict__ w, int bhL,
                                           bf16x8& lo, bf16x8& hi) {
    if (RAW) {
        const float* p = (const float*)kp + base + (long)row * DDIM + q * 8;
        float s = sqrtf(w[bhL + row] + ERRC);
        lo = pack8s(p, s);
        hi = pack8s(p + 32, s);
    } else {
        const unsigned short* p = (const unsigned short*)kp + base + (long)row * DDIM + q * 8;
        lo = *(const bf16x8*)p;
        hi = *(const bf16x8*)(p + 32);
    }
}

// One wave = one 16-column i-tile; streams 32 groups of 64 j (4 16-row tiles),
// staging each 16x128 output strip in wave-private LDS, then flushing with
// 8 stores of 2 rows x 512B contiguous (full cache lines, 1 KiB/instr).
// Swapped MFMA: D = kd_tile(j rows) . ks_rows(i)^T -> D[m=j][n=i],
// C/D: col(l16)=i, row(q*4+r)=j -> each lane holds 4 CONSECUTIVE j per tile, in-lane.
template<bool RAW>
__global__ __launch_bounds__(256, 4) void mha_fused5(const void* __restrict__ ka,  // kd (or raw k)
                                                     const void* __restrict__ kb,  // ks (or raw k)
                                                     const float* __restrict__ src,
                                                     const float* __restrict__ dest,
                                                     float* __restrict__ out) {
    __shared__ float strip[4][16 * SROW];     // 8.25 KiB per wave, wave-private (no barriers)
    const int tid  = threadIdx.x;
    const int wave = tid >> 6;
    const int lane = tid & 63;
    const int q    = lane >> 4;
    const int l16  = lane & 15;
    // bh in low bits: same-bh blocks are 32 apart -> same XCD under mod-8 dispatch.
    const int bh = blockIdx.x & 31;
    const int ib = blockIdx.x >> 5;           // 0..31
    const int i0 = (ib * 4 + wave) * 16;      // this wave's 16-column (i) tile
    const int bhL = bh * LSEQ;
    const long base = (long)bh * LSEQ * DDIM;
    float* sw = strip[wave];

    // B operand: ks row i0+l16, held for the whole kernel
    bf16x8 blo, bhi;
    load_row16<RAW>(kb, base, i0 + l16, q, src, bhL, blo, bhi);

    float carry = 0.f;                        // running row sum for output row i0+l16
    const float c23 = 2.0f / 3.0f;

    // prefetch j-tiles 0..3
    bf16x8 aLo[4], aHi[4];
#pragma unroll
    for (int t = 0; t < 4; ++t)
        load_row16<RAW>(ka, base, 16 * t + l16, q, dest, bhL, aLo[t], aHi[t]);

    // flush mapping: lanes 0..31 -> row 2s, lanes 32..63 -> row 2s+1; 4 cols/lane
    const int h2  = lane >> 5;
    const int c32 = lane & 31;
    float* obase = out + (long)(bhL + i0 + h2) * LSEQ + 4 * c32;
    const int lrd = h2 * SROW + 4 * c32;

    for (int sup = 0; sup < 16; ++sup) {
        const int j0s = sup << 7;             // strip base (128 cols)
        const bool maskedStrip = (j0s + 128) <= i0;

#pragma unroll
        for (int half = 0; half < 2; ++half) {
            const int j0 = j0s + (half << 6);
            const int colbase = half << 6;

            // prefetch next group's 4 tiles (redundant reload of tiles 0..3 at the end)
            bf16x8 nLo[4], nHi[4];
            const int jn = (j0 + 64 < LSEQ) ? (j0 + 64) : 0;
#pragma unroll
            for (int t = 0; t < 4; ++t)
                load_row16<RAW>(ka, base, jn + 16 * t + l16, q, dest, bhL, nLo[t], nHi[t]);

            // 8 MFMAs, independent across the 4 tiles
            floatx4 acc[4];
#pragma unroll
            for (int t = 0; t < 4; ++t) {
                floatx4 z4 = {0.f, 0.f, 0.f, 0.f};
                z4 = __builtin_amdgcn_mfma_f32_16x16x32_bf16(aLo[t], blo, z4, 0, 0, 0);
                acc[t] = __builtin_amdgcn_mfma_f32_16x16x32_bf16(aHi[t], bhi, z4, 0, 0, 0);
            }

            // a3 = exp2(log2(relu(a1)+err) * 2/3) — 16 independent elements
            float u[4][4];
#pragma unroll
            for (int t = 0; t < 4; ++t)
#pragma unroll
                for (int r = 0; r < 4; ++r) {
                    float v = fmaxf(acc[t][r], 0.f) + ERRC;
                    u[t][r] = exp2f(c23 * __log2f(v));
                }

            if (j0 + 64 <= i0) {
                // all 4 tiles fully below the diagonal: only the strip total feeds carry
                float s = 0.f;
#pragma unroll
                for (int t = 0; t < 4; ++t)
                    s += (u[t][0] + u[t][1]) + (u[t][2] + u[t][3]);
                float s1 = s + __shfl_xor(s, 16, 64);
                carry += s1 + __shfl_xor(s1, 32, 64);
                if (!maskedStrip) {           // mixed strip: stage the zeros for the flush
                    const floatx4 z = {0.f, 0.f, 0.f, 0.f};
#pragma unroll
                    for (int t = 0; t < 4; ++t)
                        *(floatx4*)&sw[l16 * SROW + colbase + 16 * t + 4 * q] = z;
                }
            } else {
#pragma unroll
                for (int t = 0; t < 4; ++t) {
                    const int jt0 = j0 + 16 * t;
                    float* dst = &sw[l16 * SROW + colbase + 16 * t + 4 * q];
                    if (jt0 + 16 <= i0) {
                        // fully masked tile: total only
                        float s = (u[t][0] + u[t][1]) + (u[t][2] + u[t][3]);
                        float s1 = s + __shfl_xor(s, 16, 64);
                        carry += s1 + __shfl_xor(s1, 32, 64);
                        const floatx4 z = {0.f, 0.f, 0.f, 0.f};
                        *(floatx4*)dst = z;
                    } else {
                        // in-lane inclusive prefix over this lane's 4 consecutive j
                        u[t][1] += u[t][0];
                        u[t][2] += u[t][1];
                        u[t][3] += u[t][2];
                        const float S   = u[t][3];
                        const float x16 = __shfl_xor(S, 16, 64);
                        const float s1  = S + x16;
                        const float x32 = __shfl_xor(s1, 32, 64);
                        // exclusive prefix over the 4 q-chunks + running carry
                        const float E = ((q & 1) ? x16 : 0.f) + ((q & 2) ? x32 : 0.f) + carry;
                        carry += s1 + x32;    // tile total — identical across the group
                        floatx4 o;
                        if (jt0 == i0) {      // the single mixed (diagonal) tile
#pragma unroll
                            for (int r = 0; r < 4; ++r)
                                o[r] = ((q * 4 + r) >= l16) ? (u[t][r] + E) : 0.f;
                        } else {              // fully above diagonal
#pragma unroll
                            for (int r = 0; r < 4; ++r)
                                o[r] = u[t][r] + E;
                        }
                        *(floatx4*)dst = o;
                    }
                }
            }

#pragma unroll
            for (int t = 0; t < 4; ++t) { aLo[t] = nLo[t]; aHi[t] = nHi[t]; }
        }

        // Flush the 16x128 strip: 8 instrs, each 2 rows x 512B contiguous (full lines).
        float* og = obase + j0s;
        if (maskedStrip) {
            const floatx4 z = {0.f, 0.f, 0.f, 0.f};
#pragma unroll
            for (int s = 0; s < 8; ++s)
                *(floatx4*)(og + (long)(2 * s) * LSEQ) = z;
        } else {
#pragma unroll
            for (int s = 0; s < 8; ++s) {
                floatx4 v = *(const floatx4*)&sw[lrd + 2 * s * SROW];
                *(floatx4*)(og + (long)(2 * s) * LSEQ) = v;
            }
        }
    }
}

extern "C" void kernel_launch(void* const* d_in, const int* in_sizes, int n_in,
                              void* d_out, int out_size, void* d_ws, size_t ws_size,
                              hipStream_t stream) {
    const float* k    = (const float*)d_in[0];
    const float* src  = (const float*)d_in[1];
    const float* dest = (const float*)d_in[2];
    float* out = (float*)d_out;

    const size_t half = (size_t)BH * LSEQ * DDIM * sizeof(unsigned short); // 8 MiB
    if (ws_size >= 2 * half) {
        unsigned short* ks = (unsigned short*)d_ws;
        unsigned short* kd = (unsigned short*)((char*)d_ws + half);
        prep_scaled<<<dim3(4096), dim3(256), 0, stream>>>(k, src, dest, ks, kd);
        mha_fused5<false><<<dim3(1024), dim3(256), 0, stream>>>(kd, ks, src, dest, out);
    } else {
        mha_fused5<true><<<dim3(1024), dim3(256), 0, stream>>>(k, k, src, dest, out);
    }
}